// Round 1
// baseline (758.185 us; speedup 1.0000x reference)
//
#include <hip/hip_runtime.h>

typedef __attribute__((ext_vector_type(8))) short v8s;   // 8 x bf16 (MFMA A/B frag)
typedef __attribute__((ext_vector_type(4))) float v4f;   // MFMA C/D frag
typedef unsigned short u16;
typedef unsigned int u32;

#define NRES 384
#define NN (NRES*NRES)          // 147456
#define QKVE (NN*128)           // 18874368 elems per bf16 buffer

__device__ __forceinline__ u16 f2b(float f){
  u32 u = __builtin_bit_cast(u32, f);
  u += 0x7FFFu + ((u>>16)&1u);          // RNE
  return (u16)(u>>16);
}
__device__ __forceinline__ float b2f(u16 h){
  u32 u = ((u32)h)<<16;
  return __builtin_bit_cast(float, u);
}
// XOR swizzle (G4): spread same-column rows across banks. byte-offset forms.
__device__ __forceinline__ int swz256(int row, int colb){  // 256B rows (128 bf16)
  return (row*256 + colb) ^ ((row&7)<<4);
}
__device__ __forceinline__ int swz768(int row, int colb){  // 768B rows (384 bf16)
  return (row*768 + colb) ^ ((row&7)<<4);
}

// ---------------- kernel 0: weight prep ----------------
// wts layout: 5 matrices of [128 n][128 k] bf16: 0=q(scaled),1=k,2=v,3=gate,4=o
__global__ __launch_bounds__(256) void k_prep_w(
    const float* __restrict__ qw, const float* __restrict__ kw,
    const float* __restrict__ vw, const float* __restrict__ gw,
    const float* __restrict__ ow, u16* __restrict__ wts){
  int gid = blockIdx.x*256 + threadIdx.x;    // 0..81919
  int m = gid >> 14, r = gid & 16383;
  int n = r >> 7, a = r & 127;
  const float* src = (m==0)?qw:((m==1)?kw:((m==2)?vw:((m==3)?gw:ow)));
  float v = src[a*128 + n];                  // all five are [a(=k)][n] row-major flat
  if (m==0) v *= 0.17677669529663687f;       // fold 1/sqrt(32) into q
  wts[gid] = f2b(v);                         // dst idx = m*16384 + n*128 + a == gid
}

// ---------------- kernel 1: LN + q/k/gate/v projections + feat2d bias ----------------
__global__ __launch_bounds__(256) void k_ln_proj(
    const float* __restrict__ X, const float* __restrict__ lns,
    const float* __restrict__ lnb, const float* __restrict__ f2w,
    const float* __restrict__ gb, const u16* __restrict__ wts,
    u16* __restrict__ qbuf, u16* __restrict__ kbuf,
    u16* __restrict__ vT, u16* __restrict__ gbuf, u16* __restrict__ nbb){
  __shared__ __align__(16) u16 Xs[128*128];  // swizzled bf16 LN output / later v-transpose staging
  int tid = threadIdx.x;
  int blk = blockIdx.x;                      // 1152 tiles of 128 positions
  int p0 = blk*128;
  int bi = blk/3;                            // pair row i
  int j0 = (blk%3)*128;                      // pair col base

  { // stage 1: LayerNorm, 2 threads per position
    int row = tid>>1;
    int half = (tid&1)*64;
    const float4* xp4 = (const float4*)(X + (size_t)(p0+row)*128 + half);
    float4 v[16];
    float s=0.f, ss=0.f;
    #pragma unroll
    for (int i=0;i<16;i++){ v[i]=xp4[i];
      s  += v[i].x+v[i].y+v[i].z+v[i].w;
      ss += v[i].x*v[i].x+v[i].y*v[i].y+v[i].z*v[i].z+v[i].w*v[i].w; }
    s += __shfl_xor(s,1); ss += __shfl_xor(ss,1);
    float mu = s*(1.f/128.f);
    float rstd = rsqrtf(ss*(1.f/128.f) - mu*mu + 1e-5f);
    float nb0=0,nb1=0,nb2=0,nb3=0;
    #pragma unroll
    for (int i=0;i<16;i++){
      int c = half + i*4;
      float4 sc = *(const float4*)(lns+c);
      float4 bi4= *(const float4*)(lnb+c);
      float xn0 = (v[i].x-mu)*rstd*sc.x + bi4.x;
      float xn1 = (v[i].y-mu)*rstd*sc.y + bi4.y;
      float xn2 = (v[i].z-mu)*rstd*sc.z + bi4.z;
      float xn3 = (v[i].w-mu)*rstd*sc.w + bi4.w;
      float4 fw0 = *(const float4*)(f2w + (c+0)*4);
      float4 fw1 = *(const float4*)(f2w + (c+1)*4);
      float4 fw2 = *(const float4*)(f2w + (c+2)*4);
      float4 fw3 = *(const float4*)(f2w + (c+3)*4);
      nb0 += xn0*fw0.x + xn1*fw1.x + xn2*fw2.x + xn3*fw3.x;
      nb1 += xn0*fw0.y + xn1*fw1.y + xn2*fw2.y + xn3*fw3.y;
      nb2 += xn0*fw0.z + xn1*fw1.z + xn2*fw2.z + xn3*fw3.z;
      nb3 += xn0*fw0.w + xn1*fw1.w + xn2*fw2.w + xn3*fw3.w;
      u32 pk0 = (u32)f2b(xn0) | ((u32)f2b(xn1)<<16);
      u32 pk1 = (u32)f2b(xn2) | ((u32)f2b(xn3)<<16);
      *(u32*)((char*)Xs + swz256(row, c*2))   = pk0;
      *(u32*)((char*)Xs + swz256(row, c*2+4)) = pk1;
    }
    nb0 += __shfl_xor(nb0,1); nb1 += __shfl_xor(nb1,1);
    nb2 += __shfl_xor(nb2,1); nb3 += __shfl_xor(nb3,1);
    if ((tid&1)==0){
      int pos = bi*NRES + j0 + row;
      nbb[0*NN+pos]=f2b(nb0); nbb[1*NN+pos]=f2b(nb1);
      nbb[2*NN+pos]=f2b(nb2); nbb[3*NN+pos]=f2b(nb3);
    }
  }
  __syncthreads();

  // stage 2: four 128x128 GEMMs; each wave owns 32 output cols
  int wv = tid>>6, lane = tid&63, l15 = lane&15, lhi = lane>>4;
  const v4f z4 = {0.f,0.f,0.f,0.f};
  for (int mi=0; mi<4; mi++){
    int m = mi; if (mi==2) m=3; else if (mi==3) m=2;   // order q,k,gate,v (v last: reuses Xs)
    v4f acc[8][2];
    #pragma unroll
    for (int mf=0;mf<8;mf++){ acc[mf][0]=z4; acc[mf][1]=z4; }
    for (int ks=0; ks<4; ks++){
      v8s af[8];
      #pragma unroll
      for (int mf=0;mf<8;mf++)
        af[mf] = *(const v8s*)((char*)Xs + swz256(mf*16+l15, (ks*32+lhi*8)*2));
      v8s bf[2];
      #pragma unroll
      for (int nf=0;nf<2;nf++)
        bf[nf] = *(const v8s*)(wts + m*16384 + (wv*32+nf*16+l15)*128 + ks*32 + lhi*8);
      #pragma unroll
      for (int mf=0;mf<8;mf++){
        acc[mf][0] = __builtin_amdgcn_mfma_f32_16x16x32_bf16(af[mf], bf[0], acc[mf][0],0,0,0);
        acc[mf][1] = __builtin_amdgcn_mfma_f32_16x16x32_bf16(af[mf], bf[1], acc[mf][1],0,0,0);
      }
    }
    if (mi==3){        // v: transpose via LDS so vT[b][h][d][j] global writes coalesce
      __syncthreads(); // all waves done reading Xs
      #pragma unroll
      for (int mf=0;mf<8;mf++)
        #pragma unroll
        for (int nf=0;nf<2;nf++)
          #pragma unroll
          for (int r=0;r<4;r++){
            int pr = mf*16 + lhi*4 + r;
            int n  = wv*32 + nf*16 + l15;
            *(u16*)((char*)Xs + swz256(n, pr*2)) = f2b(acc[mf][nf][r]);
          }
      __syncthreads();
      int n = tid>>1, jh = (tid&1)*64;
      int hh = n>>5, d = n&31;
      u16* dst = vT + (size_t)((bi*4+hh)*32 + d)*NRES + j0 + jh;
      #pragma unroll
      for (int i=0;i<32;i++){
        u32 val = *(u32*)((char*)Xs + swz256(n, (jh+i*2)*2));
        *(u32*)(dst + i*2) = val;
      }
    } else {
      u16* outp = (m==0)?qbuf:((m==1)?kbuf:gbuf);
      #pragma unroll
      for (int mf=0;mf<8;mf++)
        #pragma unroll
        for (int nf=0;nf<2;nf++){
          int n = wv*32 + nf*16 + l15;
          #pragma unroll
          for (int r=0;r<4;r++){
            int pr = mf*16 + lhi*4 + r;
            float val = acc[mf][nf][r];
            if (m==3) val = 1.f/(1.f+__expf(-(val + gb[n])));   // gate sigmoid
            outp[(size_t)(p0+pr)*128 + n] = f2b(val);
          }
        }
    }
  }
}

// ---------------- kernel 2: attention (per b,h, 64 q-rows) ----------------
__global__ __launch_bounds__(256) void k_attn(
    u16* qwg,                                  // q in, weighted*gate out (same buffer)
    const u16* __restrict__ kbuf, const u16* __restrict__ vT,
    const u16* __restrict__ gbuf, const u16* __restrict__ nbb,
    const float* __restrict__ mask){
  __shared__ __align__(16) char smem[49152];   // P tile (bf16, swizzled) / out-reduce overlay
  __shared__ float red[4][64];
  __shared__ float rowmax[64];
  __shared__ float rowsum[64];
  int tid = threadIdx.x;
  int qt = blockIdx.x, h = blockIdx.y, b = blockIdx.z;
  int q0 = qt*64;
  int wv = tid>>6, lane = tid&63, l15 = lane&15, lhi = lane>>4;
  const v4f z4 = {0.f,0.f,0.f,0.f};

  // QK^T: wave owns 96 keys; A (q) frags shared
  v8s qa[4];
  #pragma unroll
  for (int mf=0;mf<4;mf++)
    qa[mf] = *(const v8s*)(qwg + (size_t)(b*NRES + q0 + mf*16 + l15)*128 + h*32 + lhi*8);
  v4f s[4][6];
  #pragma unroll
  for (int mf=0;mf<4;mf++)
    #pragma unroll
    for (int nf=0;nf<6;nf++) s[mf][nf]=z4;
  #pragma unroll
  for (int nf=0;nf<6;nf++){
    int key = wv*96 + nf*16 + l15;
    v8s kb = *(const v8s*)(kbuf + (size_t)(b*NRES + key)*128 + h*32 + lhi*8);
    #pragma unroll
    for (int mf=0;mf<4;mf++)
      s[mf][nf] = __builtin_amdgcn_mfma_f32_16x16x32_bf16(qa[mf], kb, s[mf][nf],0,0,0);
  }
  // + mask bias + nonbatched bias
  #pragma unroll
  for (int nf=0;nf<6;nf++){
    int key = wv*96 + nf*16 + l15;
    float mb = 1e9f*(mask[b*NRES+key]-1.f);
    #pragma unroll
    for (int mf=0;mf<4;mf++)
      #pragma unroll
      for (int r=0;r<4;r++){
        int qr = q0 + mf*16 + lhi*4 + r;
        s[mf][nf][r] += mb + b2f(nbb[h*NN + qr*NRES + key]);
      }
  }
  // row max (over wave's 96 keys, then cross-wave)
  #pragma unroll
  for (int mf=0;mf<4;mf++)
    #pragma unroll
    for (int r=0;r<4;r++){
      float m = s[mf][0][r];
      #pragma unroll
      for (int nf=1;nf<6;nf++) m = fmaxf(m, s[mf][nf][r]);
      m = fmaxf(m, __shfl_xor(m,1)); m = fmaxf(m, __shfl_xor(m,2));
      m = fmaxf(m, __shfl_xor(m,4)); m = fmaxf(m, __shfl_xor(m,8));
      if (l15==0) red[wv][mf*16+lhi*4+r] = m;
    }
  __syncthreads();
  if (tid<64) rowmax[tid] = fmaxf(fmaxf(red[0][tid],red[1][tid]),fmaxf(red[2][tid],red[3][tid]));
  __syncthreads();
  // exp, write unnormalized P (bf16, swizzled), partial row sums
  #pragma unroll
  for (int mf=0;mf<4;mf++)
    #pragma unroll
    for (int r=0;r<4;r++){
      int rowl = mf*16+lhi*4+r;
      float mx = rowmax[rowl];
      float sum = 0.f;
      #pragma unroll
      for (int nf=0;nf<6;nf++){
        float p = __expf(s[mf][nf][r] - mx);
        sum += p;
        int key = wv*96 + nf*16 + l15;
        *(u16*)(smem + swz768(rowl, key*2)) = f2b(p);
      }
      sum += __shfl_xor(sum,1); sum += __shfl_xor(sum,2);
      sum += __shfl_xor(sum,4); sum += __shfl_xor(sum,8);
      if (l15==0) red[wv][rowl] = sum;
    }
  __syncthreads();
  if (tid<64) rowsum[tid] = red[0][tid]+red[1][tid]+red[2][tid]+red[3][tid];
  __syncthreads();   // also fences P writes before PV reads
  // PV: split-K across waves (96 keys each), d=32 in 2 n-frags
  v4f o[4][2];
  #pragma unroll
  for (int mf=0;mf<4;mf++){ o[mf][0]=z4; o[mf][1]=z4; }
  #pragma unroll
  for (int ks=0;ks<3;ks++){
    int key0 = wv*96 + ks*32;
    v8s pa[4];
    #pragma unroll
    for (int mf=0;mf<4;mf++)
      pa[mf] = *(const v8s*)(smem + swz768(mf*16+l15, (key0+lhi*8)*2));
    v8s vb[2];
    #pragma unroll
    for (int nf=0;nf<2;nf++)
      vb[nf] = *(const v8s*)(vT + (size_t)((b*4+h)*32 + nf*16 + l15)*NRES + key0 + lhi*8);
    #pragma unroll
    for (int mf=0;mf<4;mf++){
      o[mf][0] = __builtin_amdgcn_mfma_f32_16x16x32_bf16(pa[mf], vb[0], o[mf][0],0,0,0);
      o[mf][1] = __builtin_amdgcn_mfma_f32_16x16x32_bf16(pa[mf], vb[1], o[mf][1],0,0,0);
    }
  }
  __syncthreads();   // P reads done; overlay out-reduce buffer on smem
  float* outred = (float*)smem;   // [4][64][33] padded
  #pragma unroll
  for (int mf=0;mf<4;mf++)
    #pragma unroll
    for (int nf=0;nf<2;nf++)
      #pragma unroll
      for (int r=0;r<4;r++)
        outred[wv*2112 + (mf*16+lhi*4+r)*33 + nf*16+l15] = o[mf][nf][r];
  __syncthreads();
  // final: cross-wave sum, normalize, gate, write back over q
  int rowl = tid>>2, d0 = (tid&3)*8;
  float inv = 1.f/rowsum[rowl];
  size_t base = (size_t)(b*NRES + q0 + rowl)*128 + h*32;
  #pragma unroll
  for (int i=0;i<8;i++){
    int d = d0+i;
    float sv = outred[0*2112+rowl*33+d] + outred[1*2112+rowl*33+d]
             + outred[2*2112+rowl*33+d] + outred[3*2112+rowl*33+d];
    float g = b2f(gbuf[base + d]);
    qwg[base + d] = f2b(sv*inv*g);
  }
}

// ---------------- kernel 3: output projection ----------------
__global__ __launch_bounds__(256) void k_outproj(
    const u16* __restrict__ wg, const u16* __restrict__ wts,
    const float* __restrict__ ob, float* __restrict__ out){
  int tid = threadIdx.x;
  int p0 = blockIdx.x*128;
  int wv = tid>>6, lane = tid&63, l15 = lane&15, lhi = lane>>4;
  const v4f z4 = {0.f,0.f,0.f,0.f};
  v4f acc[8][2];
  #pragma unroll
  for (int mf=0;mf<8;mf++){ acc[mf][0]=z4; acc[mf][1]=z4; }
  const u16* wo = wts + 4*16384;
  #pragma unroll
  for (int ks=0;ks<4;ks++){
    v8s af[8];
    #pragma unroll
    for (int mf=0;mf<8;mf++)
      af[mf] = *(const v8s*)(wg + (size_t)(p0+mf*16+l15)*128 + ks*32 + lhi*8);
    v8s bf[2];
    #pragma unroll
    for (int nf=0;nf<2;nf++)
      bf[nf] = *(const v8s*)(wo + (wv*32+nf*16+l15)*128 + ks*32 + lhi*8);
    #pragma unroll
    for (int mf=0;mf<8;mf++){
      acc[mf][0] = __builtin_amdgcn_mfma_f32_16x16x32_bf16(af[mf], bf[0], acc[mf][0],0,0,0);
      acc[mf][1] = __builtin_amdgcn_mfma_f32_16x16x32_bf16(af[mf], bf[1], acc[mf][1],0,0,0);
    }
  }
  #pragma unroll
  for (int nf=0;nf<2;nf++){
    int n = wv*32 + nf*16 + l15;
    float obn = ob[n];
    #pragma unroll
    for (int mf=0;mf<8;mf++)
      #pragma unroll
      for (int r=0;r<4;r++)
        out[(size_t)(p0+mf*16+lhi*4+r)*128 + n] = acc[mf][nf][r] + obn;
  }
}

extern "C" void kernel_launch(void* const* d_in, const int* in_sizes, int n_in,
                              void* d_out, int out_size, void* d_ws, size_t ws_size,
                              hipStream_t stream){
  const float* pair_act = (const float*)d_in[0];
  const float* pair_mask= (const float*)d_in[1];
  const float* ln_scale = (const float*)d_in[2];
  const float* ln_bias  = (const float*)d_in[3];
  const float* f2w      = (const float*)d_in[4];
  const float* q_w      = (const float*)d_in[5];
  const float* k_w      = (const float*)d_in[6];
  const float* v_w      = (const float*)d_in[7];
  const float* g_w      = (const float*)d_in[8];
  const float* g_b      = (const float*)d_in[9];
  const float* o_w      = (const float*)d_in[10];
  const float* o_b      = (const float*)d_in[11];
  float* out = (float*)d_out;

  u16* qbuf = (u16*)d_ws;                 // q, later weighted*gate
  u16* kbuf = qbuf + (size_t)QKVE;
  u16* vT   = kbuf + (size_t)QKVE;        // [b][h][d][j]
  u16* gbuf = vT   + (size_t)QKVE;        // sigmoid(gate)
  u16* nbb  = gbuf + (size_t)QKVE;        // [h][i][j] bf16
  u16* wts  = nbb  + (size_t)(4*NN);      // 5 x 128x128 bf16

  hipLaunchKernelGGL(k_prep_w, dim3(320), dim3(256), 0, stream,
                     q_w, k_w, v_w, g_w, o_w, wts);
  hipLaunchKernelGGL(k_ln_proj, dim3(1152), dim3(256), 0, stream,
                     pair_act, ln_scale, ln_bias, f2w, g_b, wts,
                     qbuf, kbuf, vT, gbuf, nbb);
  hipLaunchKernelGGL(k_attn, dim3(6,4,384), dim3(256), 0, stream,
                     qbuf, kbuf, vT, gbuf, nbb, pair_mask);
  hipLaunchKernelGGL(k_outproj, dim3(1152), dim3(256), 0, stream,
                     qbuf, wts, o_b, out);
}